// Round 18
// baseline (300.514 us; speedup 1.0000x reference)
//
#include <hip/hip_runtime.h>
#include <math.h>

// B=4, T=4096 -> NROWS=16384; D=1024; S=2048; K=8; H=512
#define NROWS 16384
#define DDIM  1024
#define SKEYS 2048
#define KTOP  8
#define HDIM  512

typedef short  s16x8 __attribute__((ext_vector_type(8)));
typedef float  f32x4 __attribute__((ext_vector_type(4)));

#define GL16(g, l) __builtin_amdgcn_global_load_lds(                      \
    (const __attribute__((address_space(1))) void*)(g),                   \
    (__attribute__((address_space(3))) void*)(l), 16, 0, 0)

__device__ __forceinline__ float wave_sum(float v) {
#pragma unroll
    for (int off = 32; off > 0; off >>= 1) v += __shfl_xor(v, off, 64);
    return v;
}

__device__ __forceinline__ unsigned short f2bf(float f) {
    union { float f; unsigned u; } c; c.f = f;
    unsigned u = c.u;
    unsigned r = (u + 0x7FFFu + ((u >> 16) & 1u)) >> 16;
    return (unsigned short)r;
}

__device__ __forceinline__ float gelu_exact(float v) {
    return 0.5f * v * (1.0f + erff(v * 0.7071067811865475f));
}

__device__ __forceinline__ ushort4 cvt4(float4 v) {
    ushort4 o;
    o.x = f2bf(v.x); o.y = f2bf(v.y); o.z = f2bf(v.z); o.w = f2bf(v.w);
    return o;
}

// ---------- fused prep: knorm + conversions + Wq transpose ----------
// grid MUST be SKEYS (2048) blocks x 256 threads.
// bcat rows: [0,2048) = kw (filled by small GEMM); [2048,3072) = Wq;
//            [3072,3584) = gW1a.
__global__ __launch_bounds__(256) void prep_kernel(
        const float* __restrict__ x,   const float* __restrict__ Wq,
        const float* __restrict__ Wo,  const float* __restrict__ mv,
        const float* __restrict__ gW1, const float* __restrict__ mk,
        unsigned short* __restrict__ x_bf, unsigned short* __restrict__ bcat,
        unsigned short* __restrict__ wqT, unsigned short* __restrict__ wo_bf,
        unsigned short* __restrict__ mv_bf, unsigned short* __restrict__ gw1b,
        unsigned short* __restrict__ kn) {
    int bid = blockIdx.x, t = threadIdx.x;
    __shared__ float tlds[64][65];
    {
        float4 v = ((const float4*)(mk + (size_t)bid * DDIM))[t];
        float ss = v.x * v.x + v.y * v.y + v.z * v.z + v.w * v.w;
        ss = wave_sum(ss);
        __shared__ float wsum[4];
        if ((t & 63) == 0) wsum[t >> 6] = ss;
        __syncthreads();
        float tot = wsum[0] + wsum[1] + wsum[2] + wsum[3];
        float sc = 1.0f / fmaxf(sqrtf(tot), 1e-12f);
        float4 o = make_float4(v.x * sc, v.y * sc, v.z * sc, v.w * sc);
        ((ushort4*)(kn + (size_t)bid * DDIM))[t] = cvt4(o);
    }
    if (bid < 256) {
        int d0 = (bid >> 4) * 64, e0 = (bid & 15) * 64;
#pragma unroll
        for (int i = 0; i < 16; ++i) {
            int dr = i * 4 + (t >> 6);
            tlds[dr][t & 63] = Wq[(size_t)(d0 + dr) * DDIM + e0 + (t & 63)];
        }
        __syncthreads();
#pragma unroll
        for (int i = 0; i < 16; ++i) {
            int er = i * 4 + (t >> 6);
            wqT[(size_t)(e0 + er) * DDIM + d0 + (t & 63)] = f2bf(tlds[t & 63][er]);
        }
    }
    int gid = bid * 256 + t, stride = gridDim.x * 256;
    for (int i = gid; i < NROWS * DDIM / 4; i += stride)
        ((ushort4*)x_bf)[i] = cvt4(((const float4*)x)[i]);
    for (int i = gid; i < DDIM * DDIM / 4; i += stride)
        ((ushort4*)bcat)[524288 + i] = cvt4(((const float4*)Wq)[i]);
    for (int i = gid; i < HDIM * 2 * DDIM / 4; i += stride) {
        float4 v = ((const float4*)gW1)[i];
        int r = i >> 9, c4 = i & 511;
        if (c4 < 256) ((ushort4*)bcat)[786432 + r * 256 + c4] = cvt4(v);
        else          ((ushort4*)gw1b)[r * 256 + (c4 - 256)] = cvt4(v);
    }
    for (int i = gid; i < DDIM * DDIM / 4; i += stride)
        ((ushort4*)wo_bf)[i] = cvt4(((const float4*)Wo)[i]);
    for (int i = gid; i < SKEYS * DDIM / 4; i += stride)
        ((ushort4*)mv_bf)[i] = cvt4(((const float4*)mv)[i]);
}

// ---------- dual 256x256 bf16 MFMA GEMM, K=1024, BK=32, 8 waves ----------
// DOUBLE-buffered LDS (64 KB) -> 2 blocks/CU; proven round-7 hazard pattern
// scaled up: stage kt+1 -> counted vmcnt(4) -> barrier -> compute -> barrier.
// Swizzle: phys chunk = c ^ ((row>>1)&3), inverse on gload SOURCE.
// mode 0: C -> bf16.
// mode 5: tri-route by n0: [0,nsplit) keys; [nsplit,nsplit2) sumsq->qpart;
//         [nsplit2,..) bf16 -> C2.
struct GArg {
    const unsigned short* A;
    const unsigned short* B;
    unsigned short* C;
    unsigned short* C2;
    float* qpart;
    int Ncols, N2cols, nsplit, nsplit2, gx, nblocks, mode;
};

__global__ __launch_bounds__(512, 2) void dualgemm(GArg g0, GArg g1, int split) {
    __shared__ __align__(16) unsigned short As[2 * 8192];  // 2 bufs x 256x32 bf16
    __shared__ __align__(16) unsigned short Bs[2 * 8192];

    int tid = threadIdx.x, l = tid & 63, wid = tid >> 6;
    bool first = ((int)blockIdx.x < split);
    GArg g = first ? g0 : g1;
    int bid = first ? blockIdx.x : blockIdx.x - split;
    int cpx = g.nblocks >> 3;
    int sbid = (bid & 7) * cpx + (bid >> 3);
    int m0 = (sbid / g.gx) * 256;
    int n0 = (sbid % g.gx) * 256;

    int wm = wid >> 2, wn = wid & 3;   // 2 (M) x 4 (N); per-wave C = 128x64
    constexpr int NT = 32;             // K = 1024 / 32

    f32x4 acc[8][4];
#pragma unroll
    for (int i = 0; i < 8; ++i)
#pragma unroll
        for (int j = 0; j < 4; ++j) acc[i][j] = (f32x4){0.f, 0.f, 0.f, 0.f};

    // staging: issue j covers rows [j*128, j*128+128); thread -> row=t>>2,
    // 16B chunk = t&3, source chunk inverse-swizzled by (row>>1)&3.
    int srw = tid >> 2;                       // 0..127
    int sch = (tid & 3) ^ ((srw >> 1) & 3);
    int offA[2], offB[2];
#pragma unroll
    for (int j = 0; j < 2; ++j) {
        offA[j] = (m0 + j * 128 + srw) * 1024;
        offB[j] = (n0 + j * 128 + srw) * 1024;
    }
    int ldsU = wid * 512;   // ushorts: 1 KB per wave per issue

    // SPART(buf, kt, j): stage A issue j + B issue j of tile kt into buf.
#define SPART(bsel, kt_, j_)                                                   \
    do {                                                                       \
        int gk_ = (kt_) * 32 + sch * 8;                                        \
        GL16(g.A + offA[j_] + gk_, &As[(bsel) * 8192 + (j_) * 4096 + ldsU]);   \
        GL16(g.B + offB[j_] + gk_, &Bs[(bsel) * 8192 + (j_) * 4096 + ldsU]);   \
    } while (0)

    // fragment geometry (proven): row base + (l&15); chunk fp = (l>>4)^((row>>1)&3)
    int frow = l & 15;
    int fp   = (l >> 4) ^ ((frow >> 1) & 3);
    int aoff = (wm * 128 + frow) * 32 + fp * 8;   // + mf*512
    int boff = (wn * 64 + frow) * 32 + fp * 8;    // + nf*512

    // prologue: tile 0 -> buf 0 (4 issues/wave in flight)
    SPART(0, 0, 0); SPART(0, 0, 1);

    for (int kt = 0; kt < NT; ++kt) {
        int b = kt & 1;
        if (kt + 1 < NT) {
            SPART(b ^ 1, kt + 1, 0);                          // 4 new issues
            SPART(b ^ 1, kt + 1, 1);
            asm volatile("s_waitcnt vmcnt(4)" ::: "memory");  // tile kt landed
        } else {
            asm volatile("s_waitcnt vmcnt(0)" ::: "memory");
        }
        __builtin_amdgcn_s_barrier();      // all waves' tile-kt stores visible
        asm volatile("" ::: "memory");

        s16x8 af[4], bfr[4];
#pragma unroll
        for (int nf = 0; nf < 4; ++nf)
            bfr[nf] = *(const s16x8*)&Bs[b * 8192 + boff + nf * 512];
#pragma unroll
        for (int mf = 0; mf < 4; ++mf)
            af[mf] = *(const s16x8*)&As[b * 8192 + aoff + mf * 512];
        __builtin_amdgcn_s_setprio(1);
#pragma unroll
        for (int mf = 0; mf < 4; ++mf)
#pragma unroll
            for (int nf = 0; nf < 4; ++nf)
                acc[mf][nf] = __builtin_amdgcn_mfma_f32_16x16x32_bf16(
                    af[mf], bfr[nf], acc[mf][nf], 0, 0, 0);
        __builtin_amdgcn_s_setprio(0);

#pragma unroll
        for (int mf = 0; mf < 4; ++mf)
            af[mf] = *(const s16x8*)&As[b * 8192 + aoff + (mf + 4) * 512];
        __builtin_amdgcn_s_setprio(1);
#pragma unroll
        for (int mf = 0; mf < 4; ++mf)
#pragma unroll
            for (int nf = 0; nf < 4; ++nf)
                acc[mf + 4][nf] = __builtin_amdgcn_mfma_f32_16x16x32_bf16(
                    af[mf], bfr[nf], acc[mf + 4][nf], 0, 0, 0);
        __builtin_amdgcn_s_setprio(0);
        asm volatile("" ::: "memory");
        __builtin_amdgcn_s_barrier();      // readers of buf b done -> reusable
        asm volatile("" ::: "memory");
    }
#undef SPART

    // epilogue routing (block-uniform; n0 multiples of 256)
    int region = 0;   // 0 plain bf16, 1 keys, 2 qnorm-only, 3 bf16->C2
    unsigned short* cptr = g.C;
    int nc = g.Ncols, cb = n0;
    if (g.mode == 5) {
        if (n0 < g.nsplit) region = 1;
        else if (n0 < g.nsplit2) region = 2;
        else { region = 3; cptr = g.C2; nc = g.N2cols; cb = n0 - g.nsplit2; }
    }

    int crow = (l >> 4) << 2;
    int ccol = l & 15;
    if (region != 2) {
#pragma unroll
        for (int mf = 0; mf < 8; ++mf) {
            int gr = m0 + wm * 128 + mf * 16 + crow;
#pragma unroll
            for (int nf = 0; nf < 4; ++nf) {
                int gc = cb + wn * 64 + nf * 16 + ccol;
                f32x4 v = acc[mf][nf];
#pragma unroll
                for (int r2 = 0; r2 < 4; ++r2) {
                    unsigned short sv = f2bf(v[r2]);
                    if (region == 1)
                        sv = sv ^ ((sv & 0x8000) ? 0xFFFFu : 0x8000u);
                    cptr[(size_t)(gr + r2) * nc + gc] = sv;
                }
            }
        }
    } else {
        int slot = ((n0 - g.nsplit) >> 6) + wn;   // 0..15
#pragma unroll
        for (int mf = 0; mf < 8; ++mf)
#pragma unroll
            for (int r2 = 0; r2 < 4; ++r2) {
                float s = acc[mf][0][r2] * acc[mf][0][r2]
                        + acc[mf][1][r2] * acc[mf][1][r2]
                        + acc[mf][2][r2] * acc[mf][2][r2]
                        + acc[mf][3][r2] * acc[mf][3][r2];
                s += __shfl_xor(s, 1, 64);
                s += __shfl_xor(s, 2, 64);
                s += __shfl_xor(s, 4, 64);
                s += __shfl_xor(s, 8, 64);
                if ((l & 15) == 0)
                    g.qpart[(size_t)slot * NROWS +
                            (m0 + wm * 128 + mf * 16 + (l >> 4) * 4 + r2)] = s;
            }
    }
}

// ---------- bitonic top-8 helpers (descending, max-first) ----------
#define CED(k, i, j)                                                      \
    { unsigned mx_ = k[i] > k[j] ? k[i] : k[j];                           \
      unsigned mn_ = k[i] > k[j] ? k[j] : k[i];                           \
      k[i] = mx_; k[j] = mn_; }

__device__ __forceinline__ void sort8d(unsigned* k) {
    CED(k,0,1) CED(k,2,3) CED(k,4,5) CED(k,6,7)
    CED(k,0,2) CED(k,1,3) CED(k,4,6) CED(k,5,7)
    CED(k,1,2) CED(k,5,6)
    CED(k,0,4) CED(k,1,5) CED(k,2,6) CED(k,3,7)
    CED(k,2,4) CED(k,3,5)
    CED(k,1,2) CED(k,3,4) CED(k,5,6)
}

__device__ __forceinline__ void bclean8d(unsigned* t) {
    CED(t,0,4) CED(t,1,5) CED(t,2,6) CED(t,3,7)
    CED(t,0,2) CED(t,1,3) CED(t,4,6) CED(t,5,7)
    CED(t,0,1) CED(t,2,3) CED(t,4,5) CED(t,6,7)
}

__device__ __forceinline__ void merge8d(unsigned* a, const unsigned* b) {
    unsigned t[8];
#pragma unroll
    for (int i = 0; i < 8; ++i) t[i] = a[i] > b[7 - i] ? a[i] : b[7 - i];
    bclean8d(t);
#pragma unroll
    for (int i = 0; i < 8; ++i) a[i] = t[i];
}

// ---------- mega: top-8 (bitonic) + softmax + gather + gate + residual ----------
__global__ __launch_bounds__(256) void mega_kernel(
        const float* __restrict__ qpart,           // [16][NROWS] partial sumsq
        const unsigned short* __restrict__ sims,   // sortable-u16 keys
        const unsigned short* __restrict__ x_bf,
        const unsigned short* __restrict__ xg1,
        const unsigned short* __restrict__ mvo,
        const unsigned short* __restrict__ mvog,
        const float* __restrict__ gb1, const float* __restrict__ gW2,
        const float* __restrict__ gb2, float* __restrict__ out) {
    int wid = threadIdx.x >> 6, l = threadIdx.x & 63;
    int row = blockIdx.x * 4 + wid;

    const unsigned short* sr = sims + (size_t)row * SKEYS;
    uint4 raw0 = *(const uint4*)(sr + 0 * 512 + l * 8);
    uint4 raw1 = *(const uint4*)(sr + 1 * 512 + l * 8);
    uint4 raw2 = *(const uint4*)(sr + 2 * 512 + l * 8);
    uint4 raw3 = *(const uint4*)(sr + 3 * 512 + l * 8);
    const unsigned short* xr = x_bf + (size_t)row * DDIM + l * 16;
    uint4 x0 = *(const uint4*)xr, x1 = *(const uint4*)(xr + 8);
    uint4 xg = *(const uint4*)(xg1 + (size_t)row * HDIM + l * 8);

    float ssq = 0.f;
#pragma unroll
    for (int j = 0; j < 16; ++j) ssq += qpart[(size_t)j * NROWS + row];
    float qs = 1.0f / fmaxf(sqrtf(ssq), 1e-12f);

    unsigned key[32];
    {
        unsigned rw[16] = {raw0.x, raw0.y, raw0.z, raw0.w,
                           raw1.x, raw1.y, raw1.z, raw1.w,
                           raw2.x, raw2.y, raw2.z, raw2.w,
                           raw3.x, raw3.y, raw3.z, raw3.w};
#pragma unroll
        for (int c = 0; c < 4; ++c)
#pragma unroll
            for (int q2 = 0; q2 < 4; ++q2) {
                unsigned v = rw[c * 4 + q2];
                unsigned bi0 = (unsigned)(c * 512 + l * 8 + q2 * 2);
                key[c * 8 + q2 * 2]     = ((v & 0xFFFFu) << 16) | bi0;
                key[c * 8 + q2 * 2 + 1] = (v & 0xFFFF0000u) | (bi0 + 1);
            }
    }
    sort8d(key); sort8d(key + 8); sort8d(key + 16); sort8d(key + 24);
    merge8d(key, key + 8);
    merge8d(key + 16, key + 24);
    merge8d(key, key + 16);

#pragma unroll
    for (int off = 1; off <= 32; off <<= 1) {
        unsigned br[8];
#pragma unroll
        for (int i = 0; i < 8; ++i)
            br[i] = (unsigned)__shfl_xor((int)key[7 - i], off, 64);
        unsigned t[8];
#pragma unroll
        for (int i = 0; i < 8; ++i) t[i] = key[i] > br[i] ? key[i] : br[i];
        bclean8d(t);
#pragma unroll
        for (int i = 0; i < 8; ++i) key[i] = t[i];
    }

    float ov[8]; int oi[8];
#pragma unroll
    for (int j = 0; j < 8; ++j) {
        oi[j] = (int)(key[j] & 0xFFFFu);
        unsigned short ks = (unsigned short)(key[j] >> 16);
        unsigned short sv = ks ^ ((ks & 0x8000) ? 0x8000u : 0xFFFFu);
        ov[j] = __uint_as_float(((unsigned)sv) << 16);
    }
    float w[KTOP];
    float m = ov[0] * qs, ssum = 0.f;
#pragma unroll
    for (int j = 0; j < 8; ++j) { w[j] = expf(ov[j] * qs - m); ssum += w[j]; }
    float sinv = 1.0f / ssum;
#pragma unroll
    for (int j = 0; j < 8; ++j) w[j] *= sinv;

    float r2[16], hp[8];
#pragma unroll
    for (int j = 0; j < 16; ++j) r2[j] = 0.f;
#pragma unroll
    for (int j = 0; j < 8; ++j) hp[j] = 0.f;
#pragma unroll
    for (int k = 0; k < KTOP; ++k) {
        float wk = w[k];
        const unsigned short* mo = mvo + (size_t)oi[k] * DDIM + l * 16;
        uint4 a0 = *(const uint4*)mo;
        uint4 a1 = *(const uint4*)(mo + 8);
        const unsigned short* mg = mvog + (size_t)oi[k] * HDIM + l * 8;
        uint4 g0 = *(const uint4*)mg;
        unsigned aw[8] = {a0.x, a0.y, a0.z, a0.w, a1.x, a1.y, a1.z, a1.w};
#pragma unroll
        for (int j = 0; j < 8; ++j) {
            r2[2 * j]     += wk * __uint_as_float(aw[j] << 16);
            r2[2 * j + 1] += wk * __uint_as_float(aw[j] & 0xffff0000u);
        }
        unsigned gw[4] = {g0.x, g0.y, g0.z, g0.w};
#pragma unroll
        for (int j = 0; j < 4; ++j) {
            hp[2 * j]     += wk * __uint_as_float(gw[j] << 16);
            hp[2 * j + 1] += wk * __uint_as_float(gw[j] & 0xffff0000u);
        }
    }
    unsigned xgw[4] = {xg.x, xg.y, xg.z, xg.w};
    float p = 0.f;
#pragma unroll
    for (int j = 0; j < 4; ++j) {
        float h0 = gelu_exact(hp[2 * j] + __uint_as_float(xgw[j] << 16)
                              + gb1[l * 8 + 2 * j]);
        float h1 = gelu_exact(hp[2 * j + 1] + __uint_as_float(xgw[j] & 0xffff0000u)
                              + gb1[l * 8 + 2 * j + 1]);
        p += h0 * gW2[l * 8 + 2 * j] + h1 * gW2[l * 8 + 2 * j + 1];
    }
    p = wave_sum(p);
    float gate = 1.0f / (1.0f + expf(-(p + gb2[0])));
    unsigned xw[8] = {x0.x, x0.y, x0.z, x0.w, x1.x, x1.y, x1.z, x1.w};
    float o[16];
#pragma unroll
    for (int j = 0; j < 8; ++j) {
        o[2 * j]     = __uint_as_float(xw[j] << 16)         + gate * r2[2 * j];
        o[2 * j + 1] = __uint_as_float(xw[j] & 0xffff0000u) + gate * r2[2 * j + 1];
    }
    float4* po = (float4*)(out + (size_t)row * DDIM + l * 16);
    po[0] = make_float4(o[0], o[1], o[2], o[3]);
    po[1] = make_float4(o[4], o[5], o[6], o[7]);
    po[2] = make_float4(o[8], o[9], o[10], o[11]);
    po[3] = make_float4(o[12], o[13], o[14], o[15]);
}

extern "C" void kernel_launch(void* const* d_in, const int* in_sizes, int n_in,
                              void* d_out, int out_size, void* d_ws, size_t ws_size,
                              hipStream_t stream) {
    (void)in_sizes; (void)n_in; (void)out_size; (void)ws_size;
    const float* x   = (const float*)d_in[0];
    const float* mk  = (const float*)d_in[1];
    const float* mv  = (const float*)d_in[2];
    const float* Wq  = (const float*)d_in[3];
    const float* Wo  = (const float*)d_in[4];
    const float* gW1 = (const float*)d_in[5];
    const float* gb1 = (const float*)d_in[6];
    const float* gW2 = (const float*)d_in[7];
    const float* gb2 = (const float*)d_in[8];
    float* out = (float*)d_out;

    // workspace (~146 MB), lifetime-aliased
    char* w = (char*)d_ws;
    unsigned short* x_bf    = (unsigned short*)w;  w += (size_t)NROWS * DDIM * 2;
    unsigned short* xg1_bf  = (unsigned short*)w;  w += (size_t)NROWS * HDIM * 2;
    unsigned short* kn_bf   = (unsigned short*)w;  w += (size_t)SKEYS * DDIM * 2;
    unsigned short* bcat    = (unsigned short*)w;  w += (size_t)3584 * DDIM * 2;
    unsigned short* wqT_bf  = (unsigned short*)w;  w += (size_t)DDIM * DDIM * 2;
    unsigned short* gw1b_bf = (unsigned short*)w;  w += (size_t)HDIM * DDIM * 2;
    unsigned short* wo_bf   = (unsigned short*)w;  w += (size_t)DDIM * DDIM * 2;
    unsigned short* mv_bf   = (unsigned short*)w;  w += (size_t)SKEYS * DDIM * 2;
    unsigned short* mvo_bf  = (unsigned short*)w;  w += (size_t)SKEYS * DDIM * 2;
    unsigned short* mvog_bf = (unsigned short*)w;  w += (size_t)SKEYS * HDIM * 2;
    unsigned short* sims    = (unsigned short*)w;  w += (size_t)NROWS * SKEYS * 2;
    float* qpart = (float*)w;                      w += (size_t)16 * NROWS * 4;

    // 1. conversions + knorm + Wq transpose
    prep_kernel<<<SKEYS, 256, 0, stream>>>(x, Wq, Wo, mv, gW1, mk,
                                           x_bf, bcat, wqT_bf, wo_bf, mv_bf,
                                           gw1b_bf, kn_bf);

    // 2. dual small: kw = kn @ Wq -> bcat[0,2048)  ||  mvo = mv @ Wo^T
    {
        GArg gk; gk.A = kn_bf; gk.B = wqT_bf; gk.C = bcat; gk.C2 = nullptr;
        gk.qpart = nullptr; gk.Ncols = DDIM; gk.N2cols = 0;
        gk.nsplit = 0; gk.nsplit2 = 0; gk.gx = 4; gk.nblocks = 32; gk.mode = 0;
        GArg gm; gm.A = mv_bf; gm.B = wo_bf; gm.C = mvo_bf; gm.C2 = nullptr;
        gm.qpart = nullptr; gm.Ncols = DDIM; gm.N2cols = 0;
        gm.nsplit = 0; gm.nsplit2 = 0; gm.gx = 4; gm.nblocks = 32; gm.mode = 0;
        dualgemm<<<64, 512, 0, stream>>>(gk, gm, 32);
    }

    // 3. dual big: x @ bcat^T tri-routed (sims keys | qpart | xg1)  ||  mvog
    {
        GArg gb; gb.A = x_bf; gb.B = bcat; gb.C = sims; gb.C2 = xg1_bf;
        gb.qpart = qpart; gb.Ncols = SKEYS; gb.N2cols = HDIM;
        gb.nsplit = 2048; gb.nsplit2 = 3072; gb.gx = 14; gb.nblocks = 896;
        gb.mode = 5;
        GArg gg; gg.A = mvo_bf; gg.B = gw1b_bf; gg.C = mvog_bf; gg.C2 = nullptr;
        gg.qpart = nullptr; gg.Ncols = HDIM; gg.N2cols = 0;
        gg.nsplit = 0; gg.nsplit2 = 0; gg.gx = 2; gg.nblocks = 16; gg.mode = 0;
        dualgemm<<<912, 512, 0, stream>>>(gb, gg, 896);
    }

    // 4. top-8 + softmax + gather + gate + residual
    mega_kernel<<<NROWS / 4, 256, 0, stream>>>(
        qpart, sims, x_bf, xg1_bf, mvo_bf, mvog_bf, gb1, gW2, gb2, out);
}

// Round 19
// 251.334 us; speedup vs baseline: 1.1957x; 1.1957x over previous
//
#include <hip/hip_runtime.h>
#include <math.h>

// B=4, T=4096 -> NROWS=16384; D=1024; S=2048; K=8; H=512
#define NROWS 16384
#define DDIM  1024
#define SKEYS 2048
#define KTOP  8
#define HDIM  512

typedef short  s16x8 __attribute__((ext_vector_type(8)));
typedef float  f32x4 __attribute__((ext_vector_type(4)));

#define GL16(g, l) __builtin_amdgcn_global_load_lds(                      \
    (const __attribute__((address_space(1))) void*)(g),                   \
    (__attribute__((address_space(3))) void*)(l), 16, 0, 0)

__device__ __forceinline__ float wave_sum(float v) {
#pragma unroll
    for (int off = 32; off > 0; off >>= 1) v += __shfl_xor(v, off, 64);
    return v;
}

__device__ __forceinline__ unsigned short f2bf(float f) {
    union { float f; unsigned u; } c; c.f = f;
    unsigned u = c.u;
    unsigned r = (u + 0x7FFFu + ((u >> 16) & 1u)) >> 16;
    return (unsigned short)r;
}

__device__ __forceinline__ float gelu_exact(float v) {
    return 0.5f * v * (1.0f + erff(v * 0.7071067811865475f));
}

__device__ __forceinline__ ushort4 cvt4(float4 v) {
    ushort4 o;
    o.x = f2bf(v.x); o.y = f2bf(v.y); o.z = f2bf(v.z); o.w = f2bf(v.w);
    return o;
}

// ---------- fused prep: knorm + conversions + Wq transpose ----------
// grid MUST be SKEYS (2048) blocks x 256 threads.
// bcat rows: [0,2048) = kw (filled by small GEMM); [2048,3072) = Wq;
//            [3072,3584) = gW1a.
__global__ __launch_bounds__(256) void prep_kernel(
        const float* __restrict__ x,   const float* __restrict__ Wq,
        const float* __restrict__ Wo,  const float* __restrict__ mv,
        const float* __restrict__ gW1, const float* __restrict__ mk,
        unsigned short* __restrict__ x_bf, unsigned short* __restrict__ bcat,
        unsigned short* __restrict__ wqT, unsigned short* __restrict__ wo_bf,
        unsigned short* __restrict__ mv_bf, unsigned short* __restrict__ gw1b,
        unsigned short* __restrict__ kn) {
    int bid = blockIdx.x, t = threadIdx.x;
    __shared__ float tlds[64][65];
    {
        float4 v = ((const float4*)(mk + (size_t)bid * DDIM))[t];
        float ss = v.x * v.x + v.y * v.y + v.z * v.z + v.w * v.w;
        ss = wave_sum(ss);
        __shared__ float wsum[4];
        if ((t & 63) == 0) wsum[t >> 6] = ss;
        __syncthreads();
        float tot = wsum[0] + wsum[1] + wsum[2] + wsum[3];
        float sc = 1.0f / fmaxf(sqrtf(tot), 1e-12f);
        float4 o = make_float4(v.x * sc, v.y * sc, v.z * sc, v.w * sc);
        ((ushort4*)(kn + (size_t)bid * DDIM))[t] = cvt4(o);
    }
    if (bid < 256) {
        int d0 = (bid >> 4) * 64, e0 = (bid & 15) * 64;
#pragma unroll
        for (int i = 0; i < 16; ++i) {
            int dr = i * 4 + (t >> 6);
            tlds[dr][t & 63] = Wq[(size_t)(d0 + dr) * DDIM + e0 + (t & 63)];
        }
        __syncthreads();
#pragma unroll
        for (int i = 0; i < 16; ++i) {
            int er = i * 4 + (t >> 6);
            wqT[(size_t)(e0 + er) * DDIM + d0 + (t & 63)] = f2bf(tlds[t & 63][er]);
        }
    }
    int gid = bid * 256 + t, stride = gridDim.x * 256;
    for (int i = gid; i < NROWS * DDIM / 4; i += stride)
        ((ushort4*)x_bf)[i] = cvt4(((const float4*)x)[i]);
    for (int i = gid; i < DDIM * DDIM / 4; i += stride)
        ((ushort4*)bcat)[524288 + i] = cvt4(((const float4*)Wq)[i]);
    for (int i = gid; i < HDIM * 2 * DDIM / 4; i += stride) {
        float4 v = ((const float4*)gW1)[i];
        int r = i >> 9, c4 = i & 511;
        if (c4 < 256) ((ushort4*)bcat)[786432 + r * 256 + c4] = cvt4(v);
        else          ((ushort4*)gw1b)[r * 256 + (c4 - 256)] = cvt4(v);
    }
    for (int i = gid; i < DDIM * DDIM / 4; i += stride)
        ((ushort4*)wo_bf)[i] = cvt4(((const float4*)Wo)[i]);
    for (int i = gid; i < SKEYS * DDIM / 4; i += stride)
        ((ushort4*)mv_bf)[i] = cvt4(((const float4*)mv)[i]);
}

struct GArg {
    const unsigned short* A;
    const unsigned short* B;
    unsigned short* C;
    unsigned short* C2;
    float* qpart;
    int Ncols, N2cols, nsplit, nsplit2, gx, nblocks, mode;
};

// ---------- dual 128x128 bf16 MFMA GEMM (proven round-13 structure) ----------
// K=1024, BK=32, 4 waves, 32KB dbuf, 2 barriers/K-tile, vmcnt(4).
// Plain bf16 output only. For small GEMMs (better CU fill than 256^2).
__global__ __launch_bounds__(256, 3) void dualgemm128(GArg g0, GArg g1, int split) {
    __shared__ __align__(16) unsigned short As[2][4096];
    __shared__ __align__(16) unsigned short Bs[2][4096];

    int tid = threadIdx.x, l = tid & 63, wid = tid >> 6;
    bool first = ((int)blockIdx.x < split);
    GArg g = first ? g0 : g1;
    int bid = first ? blockIdx.x : blockIdx.x - split;
    int cpx = g.nblocks >> 3;
    int sbid = (bid & 7) * cpx + (bid >> 3);
    int m0 = (sbid / g.gx) * 128;
    int n0 = (sbid % g.gx) * 128;

    int wr = wid >> 1, wc = wid & 1;
    constexpr int NT = 32;

    f32x4 acc[4][4];
#pragma unroll
    for (int i = 0; i < 4; ++i)
#pragma unroll
        for (int j = 0; j < 4; ++j) acc[i][j] = (f32x4){0.f, 0.f, 0.f, 0.f};

    int srow   = tid >> 2;
    int schunk = (tid & 3) ^ ((srow >> 1) & 3);
    int offA[2], offB[2];
#pragma unroll
    for (int i = 0; i < 2; ++i) {
        offA[i] = (m0 + i * 64 + srow) * 1024;
        offB[i] = (n0 + i * 64 + srow) * 1024;
    }
    int ldsU = wid * 512;

#define STG(bsel, kt_)                                                         \
    do {                                                                       \
        int gk_ = (kt_) * 32 + schunk * 8;                                     \
        _Pragma("unroll")                                                      \
        for (int i_ = 0; i_ < 2; ++i_) {                                       \
            GL16(g.A + offA[i_] + gk_, &As[bsel][i_ * 2048 + ldsU]);           \
            GL16(g.B + offB[i_] + gk_, &Bs[bsel][i_ * 2048 + ldsU]);           \
        }                                                                      \
    } while (0)

    STG(0, 0);

    int frow = l & 15;
    int fp   = (l >> 4) ^ ((frow >> 1) & 3);
    int aoff = (wr * 64 + frow) * 32 + fp * 8;
    int boff = (wc * 64 + frow) * 32 + fp * 8;

#pragma unroll 2
    for (int kt = 0; kt < NT; ++kt) {
        int b = kt & 1;
        if (kt + 1 < NT) {
            STG(b ^ 1, kt + 1);
            asm volatile("s_waitcnt vmcnt(4)" ::: "memory");
        } else {
            asm volatile("s_waitcnt vmcnt(0)" ::: "memory");
        }
        __builtin_amdgcn_s_barrier();
        asm volatile("" ::: "memory");

        s16x8 af[4], bfr[4];
#pragma unroll
        for (int mf = 0; mf < 4; ++mf)
            af[mf] = *(const s16x8*)&As[b][aoff + mf * 512];
#pragma unroll
        for (int nf = 0; nf < 4; ++nf)
            bfr[nf] = *(const s16x8*)&Bs[b][boff + nf * 512];

        __builtin_amdgcn_s_setprio(1);
#pragma unroll
        for (int mf = 0; mf < 4; ++mf)
#pragma unroll
            for (int nf = 0; nf < 4; ++nf)
                acc[mf][nf] = __builtin_amdgcn_mfma_f32_16x16x32_bf16(
                    af[mf], bfr[nf], acc[mf][nf], 0, 0, 0);
        __builtin_amdgcn_s_setprio(0);
        asm volatile("" ::: "memory");
        __builtin_amdgcn_s_barrier();
        asm volatile("" ::: "memory");
    }
#undef STG

    int crow = (l >> 4) << 2;
    int ccol = l & 15;
#pragma unroll
    for (int mf = 0; mf < 4; ++mf) {
        int gr = m0 + wr * 64 + mf * 16 + crow;
#pragma unroll
        for (int nf = 0; nf < 4; ++nf) {
            int gc = n0 + wc * 64 + nf * 16 + ccol;
            f32x4 v = acc[mf][nf];
#pragma unroll
            for (int r2 = 0; r2 < 4; ++r2)
                g.C[(size_t)(gr + r2) * g.Ncols + gc] = f2bf(v[r2]);
        }
    }
}

// ---------- dual 256x256 bf16 MFMA GEMM, K=1024, BK=32, 8 waves ----------
// QUAD-buffered LDS (128 KB), 3-tile-deep prefetch, counted vmcnt(8),
// 1 barrier per K-tile (round-17 proven structure).
// mode 5: tri-route by n0: [0,nsplit) keys; [nsplit,nsplit2) sumsq->qpart;
//         [nsplit2,..) bf16 -> C2.  mode 0: plain bf16.
__global__ __launch_bounds__(512, 1) void dualgemm(GArg g0, GArg g1, int split) {
    __shared__ __align__(16) unsigned short As[4 * 8192];
    __shared__ __align__(16) unsigned short Bs[4 * 8192];

    int tid = threadIdx.x, l = tid & 63, wid = tid >> 6;
    bool first = ((int)blockIdx.x < split);
    GArg g = first ? g0 : g1;
    int bid = first ? blockIdx.x : blockIdx.x - split;
    int cpx = g.nblocks >> 3;
    int sbid = (bid & 7) * cpx + (bid >> 3);
    int m0 = (sbid / g.gx) * 256;
    int n0 = (sbid % g.gx) * 256;

    int wm = wid >> 2, wn = wid & 3;
    constexpr int NT = 32;

    f32x4 acc[8][4];
#pragma unroll
    for (int i = 0; i < 8; ++i)
#pragma unroll
        for (int j = 0; j < 4; ++j) acc[i][j] = (f32x4){0.f, 0.f, 0.f, 0.f};

    int srw = tid >> 2;
    int sch = (tid & 3) ^ ((srw >> 1) & 3);
    int offA[2], offB[2];
#pragma unroll
    for (int j = 0; j < 2; ++j) {
        offA[j] = (m0 + j * 128 + srw) * 1024;
        offB[j] = (n0 + j * 128 + srw) * 1024;
    }
    int ldsU = wid * 512;

#define SPART(bsel, kt_, j_)                                                   \
    do {                                                                       \
        int gk_ = (kt_) * 32 + sch * 8;                                        \
        GL16(g.A + offA[j_] + gk_, &As[(bsel) * 8192 + (j_) * 4096 + ldsU]);   \
        GL16(g.B + offB[j_] + gk_, &Bs[(bsel) * 8192 + (j_) * 4096 + ldsU]);   \
    } while (0)

    int frow = l & 15;
    int fp   = (l >> 4) ^ ((frow >> 1) & 3);
    int aoff = (wm * 128 + frow) * 32 + fp * 8;
    int boff = (wn * 64 + frow) * 32 + fp * 8;

    SPART(0, 0, 0); SPART(0, 0, 1);
    SPART(1, 1, 0); SPART(1, 1, 1);
    SPART(2, 2, 0); SPART(2, 2, 1);

    for (int kt = 0; kt < NT; ++kt) {
        int b = kt & 3;
        int b3 = (kt + 3) & 3;
        bool pf = (kt + 3 < NT);
        if (kt + 2 < NT) {
            asm volatile("s_waitcnt vmcnt(8)" ::: "memory");
        } else if (kt + 1 < NT) {
            asm volatile("s_waitcnt vmcnt(4)" ::: "memory");
        } else {
            asm volatile("s_waitcnt vmcnt(0)" ::: "memory");
        }
        __builtin_amdgcn_s_barrier();
        asm volatile("" ::: "memory");

        s16x8 af[4], bfr[4];
#pragma unroll
        for (int nf = 0; nf < 4; ++nf)
            bfr[nf] = *(const s16x8*)&Bs[b * 8192 + boff + nf * 512];
#pragma unroll
        for (int mf = 0; mf < 4; ++mf)
            af[mf] = *(const s16x8*)&As[b * 8192 + aoff + mf * 512];
        if (pf) SPART(b3, kt + 3, 0);
        __builtin_amdgcn_s_setprio(1);
#pragma unroll
        for (int mf = 0; mf < 4; ++mf)
#pragma unroll
            for (int nf = 0; nf < 4; ++nf)
                acc[mf][nf] = __builtin_amdgcn_mfma_f32_16x16x32_bf16(
                    af[mf], bfr[nf], acc[mf][nf], 0, 0, 0);
        __builtin_amdgcn_s_setprio(0);

#pragma unroll
        for (int mf = 0; mf < 4; ++mf)
            af[mf] = *(const s16x8*)&As[b * 8192 + aoff + (mf + 4) * 512];
        if (pf) SPART(b3, kt + 3, 1);
        __builtin_amdgcn_s_setprio(1);
#pragma unroll
        for (int mf = 0; mf < 4; ++mf)
#pragma unroll
            for (int nf = 0; nf < 4; ++nf)
                acc[mf + 4][nf] = __builtin_amdgcn_mfma_f32_16x16x32_bf16(
                    af[mf], bfr[nf], acc[mf + 4][nf], 0, 0, 0);
        __builtin_amdgcn_s_setprio(0);
        asm volatile("" ::: "memory");
    }
#undef SPART

    int region = 0;
    unsigned short* cptr = g.C;
    int nc = g.Ncols, cb = n0;
    if (g.mode == 5) {
        if (n0 < g.nsplit) region = 1;
        else if (n0 < g.nsplit2) region = 2;
        else { region = 3; cptr = g.C2; nc = g.N2cols; cb = n0 - g.nsplit2; }
    }

    int crow = (l >> 4) << 2;
    int ccol = l & 15;
    if (region != 2) {
#pragma unroll
        for (int mf = 0; mf < 8; ++mf) {
            int gr = m0 + wm * 128 + mf * 16 + crow;
#pragma unroll
            for (int nf = 0; nf < 4; ++nf) {
                int gc = cb + wn * 64 + nf * 16 + ccol;
                f32x4 v = acc[mf][nf];
#pragma unroll
                for (int r2 = 0; r2 < 4; ++r2) {
                    unsigned short sv = f2bf(v[r2]);
                    if (region == 1)
                        sv = sv ^ ((sv & 0x8000) ? 0xFFFFu : 0x8000u);
                    cptr[(size_t)(gr + r2) * nc + gc] = sv;
                }
            }
        }
    } else {
        int slot = ((n0 - g.nsplit) >> 6) + wn;
#pragma unroll
        for (int mf = 0; mf < 8; ++mf)
#pragma unroll
            for (int r2 = 0; r2 < 4; ++r2) {
                float s = acc[mf][0][r2] * acc[mf][0][r2]
                        + acc[mf][1][r2] * acc[mf][1][r2]
                        + acc[mf][2][r2] * acc[mf][2][r2]
                        + acc[mf][3][r2] * acc[mf][3][r2];
                s += __shfl_xor(s, 1, 64);
                s += __shfl_xor(s, 2, 64);
                s += __shfl_xor(s, 4, 64);
                s += __shfl_xor(s, 8, 64);
                if ((l & 15) == 0)
                    g.qpart[(size_t)slot * NROWS +
                            (m0 + wm * 128 + mf * 16 + (l >> 4) * 4 + r2)] = s;
            }
    }
}

// ---------- bitonic top-8 helpers (descending, max-first) ----------
#define CED(k, i, j)                                                      \
    { unsigned mx_ = k[i] > k[j] ? k[i] : k[j];                           \
      unsigned mn_ = k[i] > k[j] ? k[j] : k[i];                           \
      k[i] = mx_; k[j] = mn_; }

__device__ __forceinline__ void sort8d(unsigned* k) {
    CED(k,0,1) CED(k,2,3) CED(k,4,5) CED(k,6,7)
    CED(k,0,2) CED(k,1,3) CED(k,4,6) CED(k,5,7)
    CED(k,1,2) CED(k,5,6)
    CED(k,0,4) CED(k,1,5) CED(k,2,6) CED(k,3,7)
    CED(k,2,4) CED(k,3,5)
    CED(k,1,2) CED(k,3,4) CED(k,5,6)
}

__device__ __forceinline__ void bclean8d(unsigned* t) {
    CED(t,0,4) CED(t,1,5) CED(t,2,6) CED(t,3,7)
    CED(t,0,2) CED(t,1,3) CED(t,4,6) CED(t,5,7)
    CED(t,0,1) CED(t,2,3) CED(t,4,5) CED(t,6,7)
}

__device__ __forceinline__ void merge8d(unsigned* a, const unsigned* b) {
    unsigned t[8];
#pragma unroll
    for (int i = 0; i < 8; ++i) t[i] = a[i] > b[7 - i] ? a[i] : b[7 - i];
    bclean8d(t);
#pragma unroll
    for (int i = 0; i < 8; ++i) a[i] = t[i];
}

// ---------- mega: top-8 (bitonic) + softmax + gather + gate + residual ----------
__global__ __launch_bounds__(256) void mega_kernel(
        const float* __restrict__ qpart,
        const unsigned short* __restrict__ sims,
        const unsigned short* __restrict__ x_bf,
        const unsigned short* __restrict__ xg1,
        const unsigned short* __restrict__ mvo,
        const unsigned short* __restrict__ mvog,
        const float* __restrict__ gb1, const float* __restrict__ gW2,
        const float* __restrict__ gb2, float* __restrict__ out) {
    int wid = threadIdx.x >> 6, l = threadIdx.x & 63;
    int row = blockIdx.x * 4 + wid;

    const unsigned short* sr = sims + (size_t)row * SKEYS;
    uint4 raw0 = *(const uint4*)(sr + 0 * 512 + l * 8);
    uint4 raw1 = *(const uint4*)(sr + 1 * 512 + l * 8);
    uint4 raw2 = *(const uint4*)(sr + 2 * 512 + l * 8);
    uint4 raw3 = *(const uint4*)(sr + 3 * 512 + l * 8);
    const unsigned short* xr = x_bf + (size_t)row * DDIM + l * 16;
    uint4 x0 = *(const uint4*)xr, x1 = *(const uint4*)(xr + 8);
    uint4 xg = *(const uint4*)(xg1 + (size_t)row * HDIM + l * 8);

    float ssq = 0.f;
#pragma unroll
    for (int j = 0; j < 16; ++j) ssq += qpart[(size_t)j * NROWS + row];
    float qs = 1.0f / fmaxf(sqrtf(ssq), 1e-12f);

    unsigned key[32];
    {
        unsigned rw[16] = {raw0.x, raw0.y, raw0.z, raw0.w,
                           raw1.x, raw1.y, raw1.z, raw1.w,
                           raw2.x, raw2.y, raw2.z, raw2.w,
                           raw3.x, raw3.y, raw3.z, raw3.w};
#pragma unroll
        for (int c = 0; c < 4; ++c)
#pragma unroll
            for (int q2 = 0; q2 < 4; ++q2) {
                unsigned v = rw[c * 4 + q2];
                unsigned bi0 = (unsigned)(c * 512 + l * 8 + q2 * 2);
                key[c * 8 + q2 * 2]     = ((v & 0xFFFFu) << 16) | bi0;
                key[c * 8 + q2 * 2 + 1] = (v & 0xFFFF0000u) | (bi0 + 1);
            }
    }
    sort8d(key); sort8d(key + 8); sort8d(key + 16); sort8d(key + 24);
    merge8d(key, key + 8);
    merge8d(key + 16, key + 24);
    merge8d(key, key + 16);

#pragma unroll
    for (int off = 1; off <= 32; off <<= 1) {
        unsigned br[8];
#pragma unroll
        for (int i = 0; i < 8; ++i)
            br[i] = (unsigned)__shfl_xor((int)key[7 - i], off, 64);
        unsigned t[8];
#pragma unroll
        for (int i = 0; i < 8; ++i) t[i] = key[i] > br[i] ? key[i] : br[i];
        bclean8d(t);
#pragma unroll
        for (int i = 0; i < 8; ++i) key[i] = t[i];
    }

    float ov[8]; int oi[8];
#pragma unroll
    for (int j = 0; j < 8; ++j) {
        oi[j] = (int)(key[j] & 0xFFFFu);
        unsigned short ks = (unsigned short)(key[j] >> 16);
        unsigned short sv = ks ^ ((ks & 0x8000) ? 0x8000u : 0xFFFFu);
        ov[j] = __uint_as_float(((unsigned)sv) << 16);
    }
    float w[KTOP];
    float m = ov[0] * qs, ssum = 0.f;
#pragma unroll
    for (int j = 0; j < 8; ++j) { w[j] = expf(ov[j] * qs - m); ssum += w[j]; }
    float sinv = 1.0f / ssum;
#pragma unroll
    for (int j = 0; j < 8; ++j) w[j] *= sinv;

    float r2[16], hp[8];
#pragma unroll
    for (int j = 0; j < 16; ++j) r2[j] = 0.f;
#pragma unroll
    for (int j = 0; j < 8; ++j) hp[j] = 0.f;
#pragma unroll
    for (int k = 0; k < KTOP; ++k) {
        float wk = w[k];
        const unsigned short* mo = mvo + (size_t)oi[k] * DDIM + l * 16;
        uint4 a0 = *(const uint4*)mo;
        uint4 a1 = *(const uint4*)(mo + 8);
        const unsigned short* mg = mvog + (size_t)oi[k] * HDIM + l * 8;
        uint4 g0 = *(const uint4*)mg;
        unsigned aw[8] = {a0.x, a0.y, a0.z, a0.w, a1.x, a1.y, a1.z, a1.w};
#pragma unroll
        for (int j = 0; j < 8; ++j) {
            r2[2 * j]     += wk * __uint_as_float(aw[j] << 16);
            r2[2 * j + 1] += wk * __uint_as_float(aw[j] & 0xffff0000u);
        }
        unsigned gw[4] = {g0.x, g0.y, g0.z, g0.w};
#pragma unroll
        for (int j = 0; j < 4; ++j) {
            hp[2 * j]     += wk * __uint_as_float(gw[j] << 16);
            hp[2 * j + 1] += wk * __uint_as_float(gw[j] & 0xffff0000u);
        }
    }
    unsigned xgw[4] = {xg.x, xg.y, xg.z, xg.w};
    float p = 0.f;
#pragma unroll
    for (int j = 0; j < 4; ++j) {
        float h0 = gelu_exact(hp[2 * j] + __uint_as_float(xgw[j] << 16)
                              + gb1[l * 8 + 2 * j]);
        float h1 = gelu_exact(hp[2 * j + 1] + __uint_as_float(xgw[j] & 0xffff0000u)
                              + gb1[l * 8 + 2 * j + 1]);
        p += h0 * gW2[l * 8 + 2 * j] + h1 * gW2[l * 8 + 2 * j + 1];
    }
    p = wave_sum(p);
    float gate = 1.0f / (1.0f + expf(-(p + gb2[0])));
    unsigned xw[8] = {x0.x, x0.y, x0.z, x0.w, x1.x, x1.y, x1.z, x1.w};
    float o[16];
#pragma unroll
    for (int j = 0; j < 8; ++j) {
        o[2 * j]     = __uint_as_float(xw[j] << 16)         + gate * r2[2 * j];
        o[2 * j + 1] = __uint_as_float(xw[j] & 0xffff0000u) + gate * r2[2 * j + 1];
    }
    float4* po = (float4*)(out + (size_t)row * DDIM + l * 16);
    po[0] = make_float4(o[0], o[1], o[2], o[3]);
    po[1] = make_float4(o[4], o[5], o[6], o[7]);
    po[2] = make_float4(o[8], o[9], o[10], o[11]);
    po[3] = make_float4(o[12], o[13], o[14], o[15]);
}

extern "C" void kernel_launch(void* const* d_in, const int* in_sizes, int n_in,
                              void* d_out, int out_size, void* d_ws, size_t ws_size,
                              hipStream_t stream) {
    (void)in_sizes; (void)n_in; (void)out_size; (void)ws_size;
    const float* x   = (const float*)d_in[0];
    const float* mk  = (const float*)d_in[1];
    const float* mv  = (const float*)d_in[2];
    const float* Wq  = (const float*)d_in[3];
    const float* Wo  = (const float*)d_in[4];
    const float* gW1 = (const float*)d_in[5];
    const float* gb1 = (const float*)d_in[6];
    const float* gW2 = (const float*)d_in[7];
    const float* gb2 = (const float*)d_in[8];
    float* out = (float*)d_out;

    // workspace (~146 MB), lifetime-aliased
    char* w = (char*)d_ws;
    unsigned short* x_bf    = (unsigned short*)w;  w += (size_t)NROWS * DDIM * 2;
    unsigned short* xg1_bf  = (unsigned short*)w;  w += (size_t)NROWS * HDIM * 2;
    unsigned short* kn_bf   = (unsigned short*)w;  w += (size_t)SKEYS * DDIM * 2;
    unsigned short* bcat    = (unsigned short*)w;  w += (size_t)3584 * DDIM * 2;
    unsigned short* wqT_bf  = (unsigned short*)w;  w += (size_t)DDIM * DDIM * 2;
    unsigned short* gw1b_bf = (unsigned short*)w;  w += (size_t)HDIM * DDIM * 2;
    unsigned short* wo_bf   = (unsigned short*)w;  w += (size_t)DDIM * DDIM * 2;
    unsigned short* mv_bf   = (unsigned short*)w;  w += (size_t)SKEYS * DDIM * 2;
    unsigned short* mvo_bf  = (unsigned short*)w;  w += (size_t)SKEYS * DDIM * 2;
    unsigned short* mvog_bf = (unsigned short*)w;  w += (size_t)SKEYS * HDIM * 2;
    unsigned short* sims    = (unsigned short*)w;  w += (size_t)NROWS * SKEYS * 2;
    float* qpart = (float*)w;                      w += (size_t)16 * NROWS * 4;

    // 1. conversions + knorm + Wq transpose
    prep_kernel<<<SKEYS, 256, 0, stream>>>(x, Wq, Wo, mv, gW1, mk,
                                           x_bf, bcat, wqT_bf, wo_bf, mv_bf,
                                           gw1b_bf, kn_bf);

    // 2. dual small (128^2 tiles, 256 blocks): kw = kn @ Wq  ||  mvo = mv @ Wo^T
    {
        GArg gk; gk.A = kn_bf; gk.B = wqT_bf; gk.C = bcat; gk.C2 = nullptr;
        gk.qpart = nullptr; gk.Ncols = DDIM; gk.N2cols = 0;
        gk.nsplit = 0; gk.nsplit2 = 0; gk.gx = 8; gk.nblocks = 128; gk.mode = 0;
        GArg gm; gm.A = mv_bf; gm.B = wo_bf; gm.C = mvo_bf; gm.C2 = nullptr;
        gm.qpart = nullptr; gm.Ncols = DDIM; gm.N2cols = 0;
        gm.nsplit = 0; gm.nsplit2 = 0; gm.gx = 8; gm.nblocks = 128; gm.mode = 0;
        dualgemm128<<<256, 256, 0, stream>>>(gk, gm, 128);
    }

    // 3. dual big (256^2, quad-buf): x @ bcat^T tri-routed  ||  mvog
    {
        GArg gb; gb.A = x_bf; gb.B = bcat; gb.C = sims; gb.C2 = xg1_bf;
        gb.qpart = qpart; gb.Ncols = SKEYS; gb.N2cols = HDIM;
        gb.nsplit = 2048; gb.nsplit2 = 3072; gb.gx = 14; gb.nblocks = 896;
        gb.mode = 5;
        GArg gg; gg.A = mvo_bf; gg.B = gw1b_bf; gg.C = mvog_bf; gg.C2 = nullptr;
        gg.qpart = nullptr; gg.Ncols = HDIM; gg.N2cols = 0;
        gg.nsplit = 0; gg.nsplit2 = 0; gg.gx = 2; gg.nblocks = 16; gg.mode = 0;
        dualgemm<<<912, 512, 0, stream>>>(gb, gg, 896);
    }

    // 4. top-8 + softmax + gather + gate + residual
    mega_kernel<<<NROWS / 4, 256, 0, stream>>>(
        qpart, sims, x_bf, xg1_bf, mvo_bf, mvog_bf, gb1, gW2, gb2, out);
}